// Round 9
// baseline (58.910 us; speedup 1.0000x reference)
//
#include <hip/hip_runtime.h>

// LocallyConnected2D: out[b,p,f] = sum_k x_patch[b,p,k] * kernel[p,k,f] + bias[p,f]
// B=16, H=W=64, C=32, KH=KW=3, OH=OW=62, P=3844, F=64, fp32 in/out.
//
// MFMA formulation (R7, 55.3us): per p, M=16 batches, N=64 f, K=288.
// v_mfma_f32_16x16x16_f16; A(x): row=lane&15 (batch), k=4*(lane>>4)+j ->
// one float4/lane per k-half; B(W): col=lane&15 (f), same k -> 4 stride-Fc
// dwords; D: row=4*(lane>>4)+reg (batch), col=lane&15 (f). f16 in / fp32
// acc: absmax 1.6e-2 vs 8.9e-2 threshold.
// R8: f-split TLP fix. R7 had 3844 waves = 15.02/CU and 961 blocks -> 6.6%
// static CU imbalance (193 CUs x 4 blocks vs 63 x 3). Split each p across
// 2 waves by f-half (no reduce, no LDS, no barrier; weight bytes still
// read exactly once; only tiny L2-resident x loads duplicate): 7688 waves
// = 30/CU, acc = 8 VGPR.
// Evidence trail: R0/R3/R6 ~80us = VMEM-instruction-rate wall (broadcast
// x loads); R7 MFMA removed it; now latency/balance-bound at 88% of BW.
// Lessons: R1 = no provably wave-uniform x addrs (s_load serialization);
// R2/R5 = spill tripwire WRITE_SIZE >> 15.4MB; R4 = never narrow
// distinct-bytes per VMEM instr.

typedef _Float16 f16x4 __attribute__((ext_vector_type(4)));
typedef float    f32x4 __attribute__((ext_vector_type(4)));

namespace {
constexpr int Wc = 64, Cc = 32;
constexpr int OWc = 62;
constexpr int Pc  = 3844;
constexpr int Fc  = 64;
constexpr int KFc = 288 * 64;
constexpr size_t XB = (size_t)64 * 64 * 32;   // per-batch x stride (floats)
}

#define BTILE(ACC, T)                                                       \
    {                                                                       \
        const float* wb = wh + (T) * 16;                                    \
        f16x4 bf;                                                           \
        bf[0] = (_Float16)wb[0 * Fc];                                       \
        bf[1] = (_Float16)wb[1 * Fc];                                       \
        bf[2] = (_Float16)wb[2 * Fc];                                       \
        bf[3] = (_Float16)wb[3 * Fc];                                       \
        ACC = __builtin_amdgcn_mfma_f32_16x16x16f16(a, bf, ACC, 0, 0, 0);   \
    }

__global__ __launch_bounds__(256)
void lc2d(const float* __restrict__ x, const float* __restrict__ kern,
          const float* __restrict__ bias, float* __restrict__ out)
{
    const int t    = threadIdx.x;
    const int lane = t & 63;
    const int wv   = t >> 6;
    const int lq   = lane & 15;        // A: batch row | B/D: f-col (within 16)
    const int lg   = lane >> 4;        // k-group (and D row-group)

    const int task = blockIdx.x * 4 + wv;   // 7688 tasks, grid exact
    const int p    = task >> 1;
    const int fh   = task & 1;              // f-half: [fh*32, fh*32+32)
    const int fbase = fh << 5;

    const int oh = p / OWc;
    const int ow = p - oh * OWc;

    // A source: x[b=lq][oh+kh][ow+kw][c = khalf*16 + 4*lg + j]
    const float* xlane = x + (size_t)lq * XB + ((size_t)oh * Wc + ow) * Cc + 4 * lg;
    // B source: kern[p][k = pos*32 + khalf*16 + 4*lg + j][f = fbase + T*16 + lq]
    const float* wlane = kern + (size_t)p * KFc + (size_t)(4 * lg) * Fc + fbase + lq;

    f32x4 acc0 = {0.f, 0.f, 0.f, 0.f};
    f32x4 acc1 = {0.f, 0.f, 0.f, 0.f};

    for (int pos = 0; pos < 9; ++pos) {
        const int kh = (pos * 11) >> 5;    // pos/3 for pos<=8
        const int kw = pos - kh * 3;
        const float* xp = xlane + (size_t)(kh * Wc + kw) * Cc;
        const float* wp = wlane + (size_t)(pos * 32) * Fc;

        // A fragments: two k-halves, one float4 each (per-lane distinct 16B)
        const float4 xa0 = *(const float4*)(xp);
        const float4 xa1 = *(const float4*)(xp + 16);
        f16x4 a0, a1;
        a0[0] = (_Float16)xa0.x; a0[1] = (_Float16)xa0.y;
        a0[2] = (_Float16)xa0.z; a0[3] = (_Float16)xa0.w;
        a1[0] = (_Float16)xa1.x; a1[1] = (_Float16)xa1.y;
        a1[2] = (_Float16)xa1.z; a1[3] = (_Float16)xa1.w;

        {   // k-half 0
            const float* wh = wp;
            const f16x4 a = a0;
            BTILE(acc0, 0) BTILE(acc1, 1)
        }
        {   // k-half 1
            const float* wh = wp + 16 * Fc;
            const f16x4 a = a1;
            BTILE(acc0, 0) BTILE(acc1, 1)
        }
    }

    // Epilogue: D row = batch 4*lg + r, col f = fbase + T*16 + lq.
    const float b0 = bias[(size_t)p * Fc + fbase +  0 + lq];
    const float b1 = bias[(size_t)p * Fc + fbase + 16 + lq];
    #pragma unroll
    for (int r = 0; r < 4; ++r) {
        float* o = out + ((size_t)(4 * lg + r) * Pc + p) * Fc + fbase + lq;
        o[ 0] = acc0[r] + b0;
        o[16] = acc1[r] + b1;
    }
}

extern "C" void kernel_launch(void* const* d_in, const int* in_sizes, int n_in,
                              void* d_out, int out_size, void* d_ws, size_t ws_size,
                              hipStream_t stream)
{
    const float* x    = (const float*)d_in[0];
    const float* kern = (const float*)d_in[1];
    const float* bias = (const float*)d_in[2];
    float* out = (float*)d_out;
    dim3 grid(2 * Pc / 4);   // 1922 blocks: 4 waves = 2 p (f-split x2)
    lc2d<<<grid, 256, 0, stream>>>(x, kern, bias, out);
}

// Round 10
// 57.254 us; speedup vs baseline: 1.0289x; 1.0289x over previous
//
#include <hip/hip_runtime.h>

// LocallyConnected2D: out[b,p,f] = sum_k x_patch[b,p,k] * kernel[p,k,f] + bias[p,f]
// B=16, H=W=64, C=32, KH=KW=3, OH=OW=62, P=3844, F=64, fp32 in/out.
//
// MFMA formulation (R7, 55.3us): per p (one wave), M=16 batches, N=64 f,
// K=288. v_mfma_f32_16x16x16_f16. A(x): row=lane&15 (batch), k=4*(lane>>4)+j.
// B(W): col=lane&15 (f), same k. D: row=4*(lane>>4)+reg, col=lane&15.
// f16 in / fp32 acc: absmax 1.6e-2 vs 8.9e-2 threshold.
//
// R9: per-wave async weight pipeline (counted vmcnt, NO barriers).
// R7's weight path was 32 scalar-dword gathers (256B distinct/instr)
// consumed in-iteration -> vmcnt-FIFO dependency stalls (R8 proved more
// waves don't help: 30/CU regressed). Now each 4KB k-slice (16 rows x 64 f)
// is DMA'd to LDS with 4x global_load_lds dwordx4 (1KB contiguous/instr,
// full L2 lines), double-buffered per wave; steady-state wait is
// s_waitcnt vmcnt(4) so the next tile's loads stay in flight across the
// MFMAs. B-frags read from LDS (lgkm path, off the vmcnt critical path).
// lgkmcnt(0) before buffer reuse; sched_barrier(0) after each asm wait.
// Lessons: R1 = no provably wave-uniform x addrs; R2/R5 = spill tripwire
// WRITE>>15.4MB; R4 = never narrow distinct-bytes/VMEM-instr; R8 = not
// TLP-starved at 15 waves/CU.

typedef _Float16 f16x4 __attribute__((ext_vector_type(4)));
typedef float    f32x4 __attribute__((ext_vector_type(4)));

namespace {
constexpr int Wc = 64, Cc = 32;
constexpr int OWc = 62;
constexpr int Pc  = 3844;
constexpr int Fc  = 64;
constexpr int KFc = 288 * 64;
constexpr size_t XB = (size_t)64 * 64 * 32;   // per-batch x stride (floats)
}

#define GLD_LDS(gp, lp)                                                        \
    __builtin_amdgcn_global_load_lds(                                          \
        (const __attribute__((address_space(1))) void*)(gp),                   \
        (__attribute__((address_space(3))) void*)(lp), 16, 0, 0)

__global__ __launch_bounds__(256)
void lc2d(const float* __restrict__ x, const float* __restrict__ kern,
          const float* __restrict__ bias, float* __restrict__ out)
{
    __shared__ float wl[4][2][1024];   // [wave][buf][4KB k-slice: 16 rows x 64 f]

    const int t    = threadIdx.x;
    const int lane = t & 63;
    const int wv   = t >> 6;
    const int lq   = lane & 15;        // A: batch row | B/D: f-col (within 16)
    const int lg   = lane >> 4;        // k-group (and D row-group)

    const int p  = blockIdx.x * 4 + wv;   // grid exact: 961*4 = 3844
    const int oh = p / OWc;
    const int ow = p - oh * OWc;

    const float* kp    = kern + (size_t)p * KFc;   // weights for p (72KB, 18 slices)
    const float* xlane = x + (size_t)lq * XB + ((size_t)oh * Wc + ow) * Cc + 4 * lg;

    f32x4 acc0 = {0.f,0.f,0.f,0.f}, acc1 = {0.f,0.f,0.f,0.f};
    f32x4 acc2 = {0.f,0.f,0.f,0.f}, acc3 = {0.f,0.f,0.f,0.f};

    // ---- issue: stage k-slice s into buf b (4 x 1KB contiguous DMA) ----
    #define ISSUE(s, b)                                                        \
    {                                                                          \
        const float* g_ = kp + (size_t)(s) * 1024 + lane * 4;                  \
        GLD_LDS(g_ + 0 * 256, &wl[wv][(b)][0 * 256]);                          \
        GLD_LDS(g_ + 1 * 256, &wl[wv][(b)][1 * 256]);                          \
        GLD_LDS(g_ + 2 * 256, &wl[wv][(b)][2 * 256]);                          \
        GLD_LDS(g_ + 3 * 256, &wl[wv][(b)][3 * 256]);                          \
    }

    // ---- compute: consume k-slice s from buf b (1 x-load, 4 MFMAs) ----
    #define COMPUTE(s, b)                                                      \
    {                                                                          \
        const int pos_  = (s) >> 1;                                            \
        const int half_ = (s) & 1;                                             \
        const int kh_   = (pos_ * 11) >> 5;   /* pos/3 for pos<=8 */           \
        const int kw_   = pos_ - kh_ * 3;                                      \
        const float4 xa_ = *(const float4*)(xlane                              \
                              + (size_t)(kh_ * Wc + kw_) * Cc + half_ * 16);   \
        f16x4 a_;                                                              \
        a_[0] = (_Float16)xa_.x; a_[1] = (_Float16)xa_.y;                      \
        a_[2] = (_Float16)xa_.z; a_[3] = (_Float16)xa_.w;                      \
        const float* r_ = &wl[wv][(b)][(4 * lg) * 64 + lq];                    \
        {                                                                      \
            f16x4 bf_;                                                         \
            bf_[0]=(_Float16)r_[ 0+  0]; bf_[1]=(_Float16)r_[ 0+ 64];          \
            bf_[2]=(_Float16)r_[ 0+128]; bf_[3]=(_Float16)r_[ 0+192];          \
            acc0 = __builtin_amdgcn_mfma_f32_16x16x16f16(a_, bf_, acc0, 0,0,0);\
        }                                                                      \
        {                                                                      \
            f16x4 bf_;                                                         \
            bf_[0]=(_Float16)r_[16+  0]; bf_[1]=(_Float16)r_[16+ 64];          \
            bf_[2]=(_Float16)r_[16+128]; bf_[3]=(_Float16)r_[16+192];          \
            acc1 = __builtin_amdgcn_mfma_f32_16x16x16f16(a_, bf_, acc1, 0,0,0);\
        }                                                                      \
        {                                                                      \
            f16x4 bf_;                                                         \
            bf_[0]=(_Float16)r_[32+  0]; bf_[1]=(_Float16)r_[32+ 64];          \
            bf_[2]=(_Float16)r_[32+128]; bf_[3]=(_Float16)r_[32+192];          \
            acc2 = __builtin_amdgcn_mfma_f32_16x16x16f16(a_, bf_, acc2, 0,0,0);\
        }                                                                      \
        {                                                                      \
            f16x4 bf_;                                                         \
            bf_[0]=(_Float16)r_[48+  0]; bf_[1]=(_Float16)r_[48+ 64];          \
            bf_[2]=(_Float16)r_[48+128]; bf_[3]=(_Float16)r_[48+192];          \
            acc3 = __builtin_amdgcn_mfma_f32_16x16x16f16(a_, bf_, acc3, 0,0,0);\
        }                                                                      \
    }

    // prologue: fill both buffers
    ISSUE(0, 0)
    ISSUE(1, 1)

    // steady state: wait vmcnt(4) = "this slice's 4 loads done, next's may fly"
    for (int s = 0; s < 17; ++s) {
        asm volatile("s_waitcnt vmcnt(4)" ::: "memory");
        __builtin_amdgcn_sched_barrier(0);
        COMPUTE(s, s & 1)
        asm volatile("s_waitcnt lgkmcnt(0)" ::: "memory");   // buf reads retired
        __builtin_amdgcn_sched_barrier(0);
        if (s < 16) ISSUE(s + 2, s & 1)
    }
    // last slice: nothing newer in flight -> full drain
    asm volatile("s_waitcnt vmcnt(0)" ::: "memory");
    __builtin_amdgcn_sched_barrier(0);
    COMPUTE(17, 1)

    // Epilogue: D row = batch 4*lg + r, col f = T*16 + lq; add bias[p][f].
    const float b0 = bias[(size_t)p * Fc +  0 + lq];
    const float b1 = bias[(size_t)p * Fc + 16 + lq];
    const float b2 = bias[(size_t)p * Fc + 32 + lq];
    const float b3 = bias[(size_t)p * Fc + 48 + lq];
    #pragma unroll
    for (int r = 0; r < 4; ++r) {
        float* o = out + ((size_t)(4 * lg + r) * Pc + p) * Fc + lq;
        o[ 0] = acc0[r] + b0;
        o[16] = acc1[r] + b1;
        o[32] = acc2[r] + b2;
        o[48] = acc3[r] + b3;
    }
}

extern "C" void kernel_launch(void* const* d_in, const int* in_sizes, int n_in,
                              void* d_out, int out_size, void* d_ws, size_t ws_size,
                              hipStream_t stream)
{
    const float* x    = (const float*)d_in[0];
    const float* kern = (const float*)d_in[1];
    const float* bias = (const float*)d_in[2];
    float* out = (float*)d_out;
    dim3 grid(Pc / 4);   // 961 blocks, 1 wave per p
    lc2d<<<grid, 256, 0, stream>>>(x, kern, bias, out);
}

// Round 11
// 55.916 us; speedup vs baseline: 1.0536x; 1.0239x over previous
//
#include <hip/hip_runtime.h>

// LocallyConnected2D: out[b,p,f] = sum_k x_patch[b,p,k] * kernel[p,k,f] + bias[p,f]
// B=16, H=W=64, C=32, KH=KW=3, OH=OW=62, P=3844, F=64, fp32 in/out.
//
// MFMA formulation (R7 base, 55.3us): per p (one wave), M=16 batches,
// N=64 f, K=288. v_mfma_f32_16x16x16_f16. A(x): row=lane&15 (batch),
// k=4*(lane>>4)+j. B(W): col=lane&15 (f), same k. D: row=4*(lane>>4)+reg,
// col=lane&15. f16 in / fp32 acc: absmax 1.6e-2 vs 8.9e-2 threshold.
//
// R10: pure weight FIFO. ALL 18 A-fragments (x) are loaded and converted
// BEFORE the K-loop (afrag[18] = 36 VGPR, compile-time indexed). The
// fully-unrolled 9-pos loop then has ONLY weight dword-gathers on the
// vmcnt FIFO feeding MFMAs -> nothing forces early drains of the weight
// pipeline, and the compiler can hoist loads across pos boundaries freely.
// (R3 tested stream-separation in the WRONG regime -- the fp32 kernel was
// VMEM-instruction-bound; the MFMA kernel is weight-latency/BW-bound.)
// Lessons: R1 = no provably wave-uniform x addrs; R2/R5 = spill tripwire
// WRITE>>15.4MB (keep VGPR <= ~130, compile-time reg indexing only);
// R4 = never narrow distinct-bytes/VMEM-instr; R8 = not TLP-starved at
// 15 waves/CU; R9 = LDS round-trip for weights is neutral-to-worse.

typedef _Float16 f16x4 __attribute__((ext_vector_type(4)));
typedef float    f32x4 __attribute__((ext_vector_type(4)));

namespace {
constexpr int Wc = 64, Cc = 32;
constexpr int OWc = 62;
constexpr int Pc  = 3844;
constexpr int Fc  = 64;
constexpr int KFc = 288 * 64;
constexpr size_t XB = (size_t)64 * 64 * 32;   // per-batch x stride (floats)
}

#define BTILE(ACC, T)                                                       \
    {                                                                       \
        const float* wb = wh + (T) * 16;                                    \
        f16x4 bf;                                                           \
        bf[0] = (_Float16)wb[0 * Fc];                                       \
        bf[1] = (_Float16)wb[1 * Fc];                                       \
        bf[2] = (_Float16)wb[2 * Fc];                                       \
        bf[3] = (_Float16)wb[3 * Fc];                                       \
        ACC = __builtin_amdgcn_mfma_f32_16x16x16f16(a, bf, ACC, 0, 0, 0);   \
    }

__global__ __launch_bounds__(256)
void lc2d(const float* __restrict__ x, const float* __restrict__ kern,
          const float* __restrict__ bias, float* __restrict__ out)
{
    const int t    = threadIdx.x;
    const int lane = t & 63;
    const int wv   = t >> 6;
    const int lq   = lane & 15;        // A: batch row | B/D: f-col (within 16)
    const int lg   = lane >> 4;        // k-group (and D row-group)

    const int p  = blockIdx.x * 4 + wv;   // grid exact: 961*4 = 3844
    const int oh = p / OWc;
    const int ow = p - oh * OWc;

    const float* xlane = x + (size_t)lq * XB + ((size_t)oh * Wc + ow) * Cc + 4 * lg;
    const float* wlane = kern + (size_t)p * KFc + (size_t)(4 * lg) * Fc + lq;

    // ---- prologue: load + convert ALL A-fragments (18 x float4 -> f16x4) ----
    f16x4 afrag[18];                       // compile-time indexed only
    #pragma unroll
    for (int pos = 0; pos < 9; ++pos) {
        const int kh = (pos * 11) >> 5;    // pos/3 for pos<=8
        const int kw = pos - kh * 3;
        const float* xp = xlane + (size_t)(kh * Wc + kw) * Cc;
        const float4 xa0 = *(const float4*)(xp);
        const float4 xa1 = *(const float4*)(xp + 16);
        f16x4 a0, a1;
        a0[0] = (_Float16)xa0.x; a0[1] = (_Float16)xa0.y;
        a0[2] = (_Float16)xa0.z; a0[3] = (_Float16)xa0.w;
        a1[0] = (_Float16)xa1.x; a1[1] = (_Float16)xa1.y;
        a1[2] = (_Float16)xa1.z; a1[3] = (_Float16)xa1.w;
        afrag[2 * pos + 0] = a0;
        afrag[2 * pos + 1] = a1;
    }

    // bias early too (off the steady-state FIFO)
    const float b0 = bias[(size_t)p * Fc +  0 + lq];
    const float b1 = bias[(size_t)p * Fc + 16 + lq];
    const float b2 = bias[(size_t)p * Fc + 32 + lq];
    const float b3 = bias[(size_t)p * Fc + 48 + lq];

    f32x4 acc0 = {0.f, 0.f, 0.f, 0.f};
    f32x4 acc1 = {0.f, 0.f, 0.f, 0.f};
    f32x4 acc2 = {0.f, 0.f, 0.f, 0.f};
    f32x4 acc3 = {0.f, 0.f, 0.f, 0.f};

    // ---- steady state: pure weight-gather -> MFMA (homogeneous vmcnt) ----
    #pragma unroll
    for (int s = 0; s < 18; ++s) {         // s = pos*2 + khalf
        const float* wh = wlane + (size_t)(s * 16) * Fc;
        const f16x4 a = afrag[s];
        BTILE(acc0, 0) BTILE(acc1, 1) BTILE(acc2, 2) BTILE(acc3, 3)
    }

    // Epilogue: D row = batch 4*lg + r, col f = T*16 + lq; add bias[p][f].
    #pragma unroll
    for (int r = 0; r < 4; ++r) {
        float* o = out + ((size_t)(4 * lg + r) * Pc + p) * Fc + lq;
        o[ 0] = acc0[r] + b0;
        o[16] = acc1[r] + b1;
        o[32] = acc2[r] + b2;
        o[48] = acc3[r] + b3;
    }
}

extern "C" void kernel_launch(void* const* d_in, const int* in_sizes, int n_in,
                              void* d_out, int out_size, void* d_ws, size_t ws_size,
                              hipStream_t stream)
{
    const float* x    = (const float*)d_in[0];
    const float* kern = (const float*)d_in[1];
    const float* bias = (const float*)d_in[2];
    float* out = (float*)d_out;
    dim3 grid(Pc / 4);   // 961 blocks, 1 wave per p
    lc2d<<<grid, 256, 0, stream>>>(x, kern, bias, out);
}